// Round 9
// baseline (131.095 us; speedup 1.0000x reference)
//
#include <hip/hip_runtime.h>

// DirectVG: batched progressive box adjustment. R4 structure + pipelined
// stores: compute iter-it IoUs -> tile, compute NEXT state, THEN issue
// iter-it's nontemporal stores so they drain under iter-(it+1)'s compute.
//
// Wave = 16 rows x 4 m-groups. lane -> (r = lane&15, g = lane>>4).
// Each lane computes 25 IoUs (m = 25g+j), argmax in-lane (ascending-m strict
// '>'), reduced over the 4 g-lanes (tie -> smaller m) == jnp.argmax. Sims
// transposed through a per-wave LDS tile into coalesced dwordx4 stores.

#define BB 64
#define NN 1000
#define MM 100
#define NITER 5
#define RPW 16   // rows per wave
#define MPL 25   // gt boxes per lane
#define SSTR 100 // lsims row stride (floats)

typedef float f32x4 __attribute__((ext_vector_type(4)));  // for nt-store

__global__ __launch_bounds__(256) void dvg_kernel(
    const float* __restrict__ boxes, const float* __restrict__ gt,
    float* __restrict__ out) {
  __shared__ float4 lgt[MM];             // 1.6 KB
  __shared__ float lsims[4][RPW][SSTR];  // 25.6 KB, per-wave tiles

  const int tid = threadIdx.x;
  const int wv = tid >> 6;
  const int lane = tid & 63;
  const int r = lane & 15;
  const int g = lane >> 4;
  const int b = blockIdx.x >> 4;
  const int n0 = (blockIdx.x & 15) * 64 + wv * RPW;
  const int n = n0 + r;
  const int nc = n < NN ? n : NN - 1;  // clamp tail loads (stores masked)

  for (int i = tid; i < MM; i += 256)
    lgt[i] = reinterpret_cast<const float4*>(gt)[b * MM + i];
  __syncthreads();

  // loop-invariant gt areas for this lane's 25 columns
  float areaG[MPL];
#pragma unroll
  for (int j = 0; j < MPL; ++j) {
    const float4 q = lgt[g * MPL + j];
    float a = (q.z - q.x) * (q.w - q.y);
    asm("" : "+v"(a));
    areaG[j] = a;
  }

  const float4 bx = reinterpret_cast<const float4*>(boxes)[b * NN + nc];
  float b0 = bx.x, b1 = bx.y, b2 = bx.z, b3 = bx.w;

  float* __restrict__ outB = out;                            // [B,6,N,4]
  float* __restrict__ outS = out + (size_t)BB * 6 * NN * 4;  // [B,6,N,M]

  // boxes-out transpose: target lane l=4r'+c pulls from src lane 16c+r'
  const int bp_addr = ((((lane & 3) << 4) + (lane >> 2)) << 2);
  const int rr = lane >> 2;        // row for coalesced store phases
  const int q4 = (lane & 3) << 2;  // starting col (floats) within phase
  const bool rowok = (n0 + rr) < NN;

  for (int it = 0;; ++it) {
    float area = (b2 - b0) * (b3 - b1);
    asm("" : "+v"(area));

    // 1) 25 IoUs + in-lane first-occurrence argmax + tile staging
    float best = -1.0f;
    int bim = 0;
    {
      float* ls = &lsims[wv][r][g * MPL];
#pragma unroll
      for (int j = 0; j < MPL; ++j) {
        const float4 q = lgt[g * MPL + j];
        const float ltx = fmaxf(b0, q.x), lty = fmaxf(b1, q.y);
        const float rbx = fminf(b2, q.z), rby = fminf(b3, q.w);
        const float w = fmaxf(rbx - ltx, 0.0f);
        const float h = fmaxf(rby - lty, 0.0f);
        float inter = w * h;
        asm("" : "+v"(inter));
        const float uni = (area + areaG[j]) - inter;
        const float val = inter * __builtin_amdgcn_rcpf(uni);
        ls[j] = val;
        const bool t = val > best;  // strict >: first occurrence in-lane
        best = t ? val : best;
        bim = t ? g * MPL + j : bim;
      }
    }

    // 2) boxes transpose from CURRENT state (held in a reg until store)
    const float tcomp = g == 0 ? b0 : (g == 1 ? b1 : (g == 2 ? b2 : b3));
    const float bt = __int_as_float(
        __builtin_amdgcn_ds_bpermute(bp_addr, __float_as_int(tcomp)));

    const size_t obase = (size_t)(b * 6 + it) * NN + n0;
    const bool last = (it == NITER);

    // 3) next state (temps) -- before the stores so they can drain late
    float nb0 = b0, nb1 = b1, nb2 = b2, nb3 = b3;
    if (!last) {
#pragma unroll
      for (int off = 16; off <= 32; off <<= 1) {
        const float ov = __shfl_xor(best, off, 64);
        const int obi = __shfl_xor(bim, off, 64);
        const bool t = (ov > best) || (ov == best && obi < bim);
        best = t ? ov : best;
        bim = t ? obi : bim;
      }
      const float4 gg = lgt[bim];  // uniform -> broadcast
      const float dcx = (gg.x + gg.z) * 0.5f - (b0 + b2) * 0.5f;
      const float dcy = (gg.y + gg.w) * 0.5f - (b1 + b3) * 0.5f;
      const float dsx = (gg.z - gg.x) - (b2 - b0);
      const float dsy = (gg.w - gg.y) - (b3 - b1);
      float px = 0.45f * dcx;
      asm("" : "+v"(px));
      float py = 0.45f * dcy;
      asm("" : "+v"(py));
      float qx = 0.4f * (dsx - dcx);
      asm("" : "+v"(qx));
      float qy = 0.4f * (dsy - dcy);
      asm("" : "+v"(qy));
      nb0 = b0 + px;
      nb1 = b1 + py;
      nb2 = (b2 + px) + qx;
      nb3 = (b3 + py) + qy;
    }

    // 4) nontemporal stores (write-once stream; drain under next iter)
    if (rowok) __builtin_nontemporal_store(bt, &outB[obase * 4 + lane]);
    {
      const float* lsr = &lsims[wv][0][0];
      float* os = outS + obase * MM;
#pragma unroll
      for (int i = 0; i < 7; ++i) {
        const int q = i * 4 + (lane & 3);  // quad index 0..27
        if (q < MPL && rowok) {
          const f32x4 d =
              *reinterpret_cast<const f32x4*>(&lsr[rr * SSTR + i * 16 + q4]);
          __builtin_nontemporal_store(
              d, reinterpret_cast<f32x4*>(&os[(size_t)rr * MM + i * 16 + q4]));
        }
      }
    }

    if (last) break;
    b0 = nb0; b1 = nb1; b2 = nb2; b3 = nb3;
  }
}

extern "C" void kernel_launch(void* const* d_in, const int* in_sizes, int n_in,
                              void* d_out, int out_size, void* d_ws,
                              size_t ws_size, hipStream_t stream) {
  const float* boxes = (const float*)d_in[0];
  const float* gt = (const float*)d_in[1];
  float* out = (float*)d_out;
  // 16 blocks per batch (16 waves x 16 rows = 1024 >= 1000 rows)
  dvg_kernel<<<BB * 16, 256, 0, stream>>>(boxes, gt, out);
}

// Round 10
// 38.283 us; speedup vs baseline: 3.4243x; 3.4243x over previous
//
#include <hip/hip_runtime.h>

// DirectVG: batched progressive box adjustment. R4 structure + pipelined
// store ordering (compute next state BEFORE issuing current stores), with
// NORMAL stores (nt-store experiment in R9 caused 1.7x HBM write
// amplification by bypassing L2 write-combining: 275MB written for a 160MB
// output, 35.9 -> 131us. Streaming stores must go through L2 on gfx950).
//
// Wave = 16 rows x 4 m-groups. lane -> (r = lane&15, g = lane>>4).
// Each lane computes 25 IoUs (m = 25g+j), argmax in-lane (ascending-m strict
// '>'), reduced over the 4 g-lanes (tie -> smaller m) == jnp.argmax. Sims
// transposed through a per-wave LDS tile into coalesced dwordx4 stores.

#define BB 64
#define NN 1000
#define MM 100
#define NITER 5
#define RPW 16   // rows per wave
#define MPL 25   // gt boxes per lane
#define SSTR 100 // lsims row stride (floats)

__global__ __launch_bounds__(256) void dvg_kernel(
    const float* __restrict__ boxes, const float* __restrict__ gt,
    float* __restrict__ out) {
  __shared__ float4 lgt[MM];             // 1.6 KB
  __shared__ float lsims[4][RPW][SSTR];  // 25.6 KB, per-wave tiles

  const int tid = threadIdx.x;
  const int wv = tid >> 6;
  const int lane = tid & 63;
  const int r = lane & 15;
  const int g = lane >> 4;
  const int b = blockIdx.x >> 4;
  const int n0 = (blockIdx.x & 15) * 64 + wv * RPW;
  const int n = n0 + r;
  const int nc = n < NN ? n : NN - 1;  // clamp tail loads (stores masked)

  for (int i = tid; i < MM; i += 256)
    lgt[i] = reinterpret_cast<const float4*>(gt)[b * MM + i];
  __syncthreads();

  // loop-invariant gt areas for this lane's 25 columns
  float areaG[MPL];
#pragma unroll
  for (int j = 0; j < MPL; ++j) {
    const float4 q = lgt[g * MPL + j];
    float a = (q.z - q.x) * (q.w - q.y);
    asm("" : "+v"(a));
    areaG[j] = a;
  }

  const float4 bx = reinterpret_cast<const float4*>(boxes)[b * NN + nc];
  float b0 = bx.x, b1 = bx.y, b2 = bx.z, b3 = bx.w;

  float* __restrict__ outB = out;                            // [B,6,N,4]
  float* __restrict__ outS = out + (size_t)BB * 6 * NN * 4;  // [B,6,N,M]

  // boxes-out transpose: target lane l=4r'+c pulls from src lane 16c+r'
  const int bp_addr = ((((lane & 3) << 4) + (lane >> 2)) << 2);
  const int rr = lane >> 2;        // row for coalesced store phases
  const int q4 = (lane & 3) << 2;  // starting col (floats) within phase
  const bool rowok = (n0 + rr) < NN;

  for (int it = 0;; ++it) {
    float area = (b2 - b0) * (b3 - b1);
    asm("" : "+v"(area));

    // 1) 25 IoUs + in-lane first-occurrence argmax + tile staging
    float best = -1.0f;
    int bim = 0;
    {
      float* ls = &lsims[wv][r][g * MPL];
#pragma unroll
      for (int j = 0; j < MPL; ++j) {
        const float4 q = lgt[g * MPL + j];
        const float ltx = fmaxf(b0, q.x), lty = fmaxf(b1, q.y);
        const float rbx = fminf(b2, q.z), rby = fminf(b3, q.w);
        const float w = fmaxf(rbx - ltx, 0.0f);
        const float h = fmaxf(rby - lty, 0.0f);
        float inter = w * h;
        asm("" : "+v"(inter));
        const float uni = (area + areaG[j]) - inter;
        const float val = inter * __builtin_amdgcn_rcpf(uni);
        ls[j] = val;
        const bool t = val > best;  // strict >: first occurrence in-lane
        best = t ? val : best;
        bim = t ? g * MPL + j : bim;
      }
    }

    // 2) boxes transpose from CURRENT state (held in a reg until store)
    const float tcomp = g == 0 ? b0 : (g == 1 ? b1 : (g == 2 ? b2 : b3));
    const float bt = __int_as_float(
        __builtin_amdgcn_ds_bpermute(bp_addr, __float_as_int(tcomp)));

    const size_t obase = (size_t)(b * 6 + it) * NN + n0;
    const bool last = (it == NITER);

    // 3) next state (temps) -- before the stores so they can drain late
    float nb0 = b0, nb1 = b1, nb2 = b2, nb3 = b3;
    if (!last) {
#pragma unroll
      for (int off = 16; off <= 32; off <<= 1) {
        const float ov = __shfl_xor(best, off, 64);
        const int obi = __shfl_xor(bim, off, 64);
        const bool t = (ov > best) || (ov == best && obi < bim);
        best = t ? ov : best;
        bim = t ? obi : bim;
      }
      const float4 gg = lgt[bim];  // uniform -> broadcast
      const float dcx = (gg.x + gg.z) * 0.5f - (b0 + b2) * 0.5f;
      const float dcy = (gg.y + gg.w) * 0.5f - (b1 + b3) * 0.5f;
      const float dsx = (gg.z - gg.x) - (b2 - b0);
      const float dsy = (gg.w - gg.y) - (b3 - b1);
      float px = 0.45f * dcx;
      asm("" : "+v"(px));
      float py = 0.45f * dcy;
      asm("" : "+v"(py));
      float qx = 0.4f * (dsx - dcx);
      asm("" : "+v"(qx));
      float qy = 0.4f * (dsy - dcy);
      asm("" : "+v"(qy));
      nb0 = b0 + px;
      nb1 = b1 + py;
      nb2 = (b2 + px) + qx;
      nb3 = (b3 + py) + qy;
    }

    // 4) regular stores (L2 write-combining assembles full lines)
    if (rowok) outB[obase * 4 + lane] = bt;
    {
      const float* lsr = &lsims[wv][0][0];
      float* os = outS + obase * MM;
#pragma unroll
      for (int i = 0; i < 7; ++i) {
        const int q = i * 4 + (lane & 3);  // quad index 0..27
        if (q < MPL && rowok) {
          const float4 d =
              *reinterpret_cast<const float4*>(&lsr[rr * SSTR + i * 16 + q4]);
          *reinterpret_cast<float4*>(&os[(size_t)rr * MM + i * 16 + q4]) = d;
        }
      }
    }

    if (last) break;
    b0 = nb0; b1 = nb1; b2 = nb2; b3 = nb3;
  }
}

extern "C" void kernel_launch(void* const* d_in, const int* in_sizes, int n_in,
                              void* d_out, int out_size, void* d_ws,
                              size_t ws_size, hipStream_t stream) {
  const float* boxes = (const float*)d_in[0];
  const float* gt = (const float*)d_in[1];
  float* out = (float*)d_out;
  // 16 blocks per batch (16 waves x 16 rows = 1024 >= 1000 rows)
  dvg_kernel<<<BB * 16, 256, 0, stream>>>(boxes, gt, out);
}